// Round 4
// baseline (120.661 us; speedup 1.0000x reference)
//
#include <hip/hip_runtime.h>
#include <hip/hip_bf16.h>

#define T_DIM 6
#define N_NODES 10000
#define TOTAL_ROWS (T_DIM * N_NODES)   // 60000
#define LOG2E 1.44269504088896340736f
#define QPRE (0.25f * LOG2E)           // dh^-0.5 * log2(e): softmax done in exp2 domain
#define EPS_GATE 1e-6f
#define NEGBIG (-1e30f)

typedef unsigned int u32;
typedef unsigned short u16;
typedef __attribute__((ext_vector_type(8))) short bf16x8;
typedef __attribute__((ext_vector_type(4))) float f32x4;

#define MFMA16(a, b, c) __builtin_amdgcn_mfma_f32_16x16x32_bf16(a, b, c, 0, 0, 0)

__device__ __forceinline__ float fast_exp2(float x) {
#if __has_builtin(__builtin_amdgcn_exp2f)
    return __builtin_amdgcn_exp2f(x);
#else
    return exp2f(x);
#endif
}

// DPP butterfly add within 8-lane groups.
template <int CTRL>
__device__ __forceinline__ float dpp_add(float x) {
    int v = __builtin_amdgcn_update_dpp(0, __float_as_int(x), CTRL, 0xf, 0xf, true);
    return x + __int_as_float(v);
}
__device__ __forceinline__ float red8(float x) {
    x = dpp_add<0xB1>(x);   // quad_perm {1,0,3,2}  : lane ^ 1
    x = dpp_add<0x4E>(x);   // quad_perm {2,3,0,1}  : lane ^ 2
    x = dpp_add<0x141>(x);  // row_half_mirror      : l -> 7-l within 8
    return x;
}

__device__ __forceinline__ float bf2f(u16 u) {
    union { unsigned int i; float f; } c;
    c.i = ((unsigned int)u) << 16;
    return c.f;
}

__device__ __forceinline__ u16 f2bf(float f) {
    union { float f; unsigned int i; } c; c.f = f;
    unsigned int i = c.i;
    unsigned int lsb = (i >> 16) & 1u;
    i += 0x7FFFu + lsb;          // round-to-nearest-even (finite data only)
    return (u16)(i >> 16);
}

// ---------------- CSR build: histogram + scan + scatter, one block, LDS-resident ----------------
#define SCAN_THREADS 1024
#define SCAN_CHUNK 10            // 1024*10 >= 10000
__global__ __launch_bounds__(SCAN_THREADS) void csr_kernel(
    const int* __restrict__ esrc, const int* __restrict__ edst,
    int* __restrict__ row_ptr,    // N+1
    int* __restrict__ edge_src, int E) {
    __shared__ int hist[N_NODES];        // 40 KB: histogram, then cursor
    __shared__ int sums[SCAN_THREADS];   // 4 KB
    int tid = threadIdx.x;
    for (int i = tid; i < N_NODES; i += SCAN_THREADS) hist[i] = 0;
    __syncthreads();
    for (int e = tid; e < E; e += SCAN_THREADS) atomicAdd(&hist[edst[e]], 1);
    __syncthreads();

    int start = tid * SCAN_CHUNK;
    int local[SCAN_CHUNK];
    int s = 0;
    #pragma unroll
    for (int j = 0; j < SCAN_CHUNK; ++j) {
        int idx = start + j;
        int v = (idx < N_NODES) ? hist[idx] : 0;
        local[j] = s; s += v;
    }
    sums[tid] = s;
    __syncthreads();
    for (int off = 1; off < SCAN_THREADS; off <<= 1) {
        int v = sums[tid];
        int o = (tid >= off) ? sums[tid - off] : 0;
        __syncthreads();
        sums[tid] = v + o;
        __syncthreads();
    }
    int base = (tid > 0) ? sums[tid - 1] : 0;
    #pragma unroll
    for (int j = 0; j < SCAN_CHUNK; ++j) {
        int idx = start + j;
        if (idx < N_NODES) {
            int st = base + local[j];
            row_ptr[idx] = st;
            hist[idx] = st;              // hist becomes the scatter cursor
        }
    }
    if (tid == SCAN_THREADS - 1) row_ptr[N_NODES] = sums[SCAN_THREADS - 1];
    __syncthreads();

    // scatter via LDS-atomic cursors; global stores are fire-and-forget
    for (int e = tid; e < E; e += SCAN_THREADS) {
        int d = edst[e];
        int sv = esrc[e];
        int pos = atomicAdd(&hist[d], 1);
        edge_src[pos] = sv;
    }
}

// ---------------- fused prep + QKV projection via split-bf16 MFMA ----------------
// Prep part: gate = log2(S+eps) transposed [n][t]; kpe/bias tables (block 0).
// GEMM part: C[row, col] = sum_k H[row,k]*W[col,k], cols 0-63 Q, 64-127 K, 128-191 V.
// f32 accuracy recovered via h = hi + lo (bf16 pair): h*w ~= hi*whi + hi*wlo + lo*whi.
__global__ __launch_bounds__(256) void proj_kernel(
    const float* __restrict__ H,
    const float* __restrict__ S,
    const float* __restrict__ Wq, const float* __restrict__ Wk,
    const float* __restrict__ Wv,
    float* __restrict__ Qs, u16* __restrict__ Kb, u16* __restrict__ Vb,
    float* __restrict__ gate, float* __restrict__ kpe, float* __restrict__ bias) {
    int tid = threadIdx.x;
    // ---- fused prep ----
    int gtid = blockIdx.x * 256 + tid;
    if (gtid < TOTAL_ROWS) {
        int t = gtid / N_NODES, n = gtid - t * N_NODES;
        gate[n * T_DIM + t] = log2f(S[gtid] + EPS_GATE);
    }
    if (blockIdx.x == 0 && tid < 64) {
        int c = tid;
        for (int dt = 0; dt < 9; ++dt) {
            float fdt = (float)dt;
            float pe[8];
            pe[0] = expf(-fdt * 0.25f);    // tau=4
            pe[1] = expf(-fdt * 0.0625f);  // tau=16
            pe[2] = sinf(fdt * 1.0f);
            pe[3] = sinf(fdt * 0.5f);
            pe[4] = sinf(fdt * 0.25f);
            pe[5] = cosf(fdt * 1.0f);
            pe[6] = cosf(fdt * 0.5f);
            pe[7] = cosf(fdt * 0.25f);
            float acc = 0.f;
            #pragma unroll
            for (int j = 0; j < 8; ++j) acc += pe[j] * Wk[c * 72 + 64 + j];
            kpe[dt * 64 + c] = acc;
            if (c == 0) bias[dt] = -log2f(1.0f + fdt);
        }
    }

    // ---- weight staging ----
    __shared__ short whi[192][72];   // stride 72 shorts = 144B -> 2-way banks (free)
    __shared__ short wlo[192][72];
    for (int i = tid; i < 192 * 64; i += 256) {
        int col = i >> 6, k = i & 63;
        float w;
        if (col < 64)       w = Wq[col * 64 + k];
        else if (col < 128) w = Wk[(col - 64) * 72 + k];   // first 64 input dims of W_k
        else                w = Wv[(col - 128) * 64 + k];
        u16 hb = f2bf(w);
        u16 lb = f2bf(w - bf2f(hb));
        whi[col][k] = (short)hb;
        wlo[col][k] = (short)lb;
    }
    __syncthreads();

    int lane = tid & 63, wid = tid >> 6;
    int r0 = (blockIdx.x * 4 + wid) * 32;          // 32 rows per wave (60000 = 32*1875)
    if (r0 >= TOTAL_ROWS) return;

    int mrow = lane & 15;
    int kgrp = lane >> 4;                          // 0..3

    // A fragments: [mtile][kstep], hi+lo split
    bf16x8 ahi[2][2], alo[2][2];
    #pragma unroll
    for (int mt = 0; mt < 2; ++mt) {
        #pragma unroll
        for (int ks = 0; ks < 2; ++ks) {
            const float* hp = H + (size_t)(r0 + mt * 16 + mrow) * 64 + ks * 32 + kgrp * 8;
            float4 hA = *(const float4*)hp;
            float4 hB = *(const float4*)(hp + 4);
            float tmp[8] = {hA.x, hA.y, hA.z, hA.w, hB.x, hB.y, hB.z, hB.w};
            #pragma unroll
            for (int b = 0; b < 8; ++b) {
                u16 hb = f2bf(tmp[b]);
                u16 lb = f2bf(tmp[b] - bf2f(hb));
                ahi[mt][ks][b] = (short)hb;
                alo[mt][ks][b] = (short)lb;
            }
        }
    }

    #pragma unroll
    for (int nt = 0; nt < 12; ++nt) {
        f32x4 acc0 = {0.f, 0.f, 0.f, 0.f};
        f32x4 acc1 = {0.f, 0.f, 0.f, 0.f};
        #pragma unroll
        for (int ks = 0; ks < 2; ++ks) {
            bf16x8 bh = *(const bf16x8*)&whi[nt * 16 + mrow][ks * 32 + kgrp * 8];
            bf16x8 bl = *(const bf16x8*)&wlo[nt * 16 + mrow][ks * 32 + kgrp * 8];
            acc0 = MFMA16(ahi[0][ks], bh, acc0);
            acc0 = MFMA16(ahi[0][ks], bl, acc0);
            acc0 = MFMA16(alo[0][ks], bh, acc0);
            acc1 = MFMA16(ahi[1][ks], bh, acc1);
            acc1 = MFMA16(ahi[1][ks], bl, acc1);
            acc1 = MFMA16(alo[1][ks], bh, acc1);
        }
        // epilogue: C col = lane&15, row = (lane>>4)*4 + j   [m89-verified]
        #pragma unroll
        for (int mt = 0; mt < 2; ++mt) {
            f32x4 acc = mt ? acc1 : acc0;
            int mbase = r0 + mt * 16 + kgrp * 4;
            #pragma unroll
            for (int j = 0; j < 4; ++j) {
                int gr = mbase + j;
                float v = acc[j];
                if (nt < 4) {
                    Qs[(size_t)gr * 64 + nt * 16 + mrow] = v * QPRE;
                } else if (nt < 8) {
                    int t = gr / N_NODES, n = gr - t * N_NODES;
                    Kb[((size_t)n * T_DIM + t) * 64 + (nt - 4) * 16 + mrow] = f2bf(v);
                } else {
                    int t = gr / N_NODES, n = gr - t * N_NODES;
                    Vb[((size_t)n * T_DIM + t) * 64 + (nt - 8) * 16 + mrow] = f2bf(v);
                }
            }
        }
    }
}

// ---------------- aggregation: one wave per node, 2 edges per iteration ----------------
// lanes: [half(2 edges)][head(4)][pair(8)], each lane owns 2 consecutive dims.
__global__ __launch_bounds__(256) void agg_kernel(
    const float* __restrict__ Qs,     // [t][n][64], prescaled by QPRE (aliases out)
    const u16* __restrict__ Kb,       // [n][t][64] bf16
    const u16* __restrict__ Vb,
    const float* __restrict__ gate,   // [n][t]  log2(S+eps)
    const float* __restrict__ kpe,    // [9][64]
    const float* __restrict__ bias,   // [9]  -log2(1+dt)
    const int* __restrict__ row_ptr,
    const int* __restrict__ edge_src,
    float* __restrict__ out) {
    int lane = threadIdx.x & 63, w = threadIdx.x >> 6;
    int n = blockIdx.x * 4 + w;
    int half = lane >> 5;
    int l32 = lane & 31;
    int doff = ((l32 >> 3) << 4) + ((l32 & 7) << 1);   // h*16 + 2*p

    float q0[T_DIM], q1[T_DIM];
    #pragma unroll
    for (int t = 0; t < T_DIM; ++t) {
        float2 qq = *(const float2*)(Qs + ((size_t)t * N_NODES + n) * 64 + doff);
        q0[t] = qq.x; q1[t] = qq.y;
    }

    int e0 = row_ptr[n], e1 = row_ptr[n + 1];
    if (e0 >= e1) {                                    // zero-degree: output 0 (matches ref clip)
        if (half == 0) {
            #pragma unroll
            for (int t = 0; t < T_DIM; ++t)
                *(float2*)(out + ((size_t)t * N_NODES + n) * 64 + doff) = make_float2(0.f, 0.f);
        }
        return;
    }

    // cc[tri(t,dt)] = dot(q[t], K_pe[dt]) + bias[dt]   (log2 domain; uniform per head group)
    float cc[21];
    #pragma unroll
    for (int dt = 0; dt < T_DIM; ++dt) {
        float2 kp = *(const float2*)(kpe + dt * 64 + doff);
        float b = bias[dt];
        #pragma unroll
        for (int t = dt; t < T_DIM; ++t)
            cc[t * (t + 1) / 2 + dt] = red8(fmaf(q1[t], kp.y, q0[t] * kp.x)) + b;
    }

    float den[T_DIM] = {0,0,0,0,0,0};
    float nu0[T_DIM] = {0,0,0,0,0,0};
    float nu1[T_DIM] = {0,0,0,0,0,0};

    int npairs = (e1 - e0 + 1) >> 1;
    u32 ku[T_DIM], vu[T_DIM];
    float gg[T_DIM];

    // prologue: load pair 0 (this half's edge; odd tail padded via g = -1e30 -> weight 0)
    {
        int i = e0 + half;
        int s = edge_src[min(i, e1 - 1)];
        const u16* kb = Kb + (size_t)s * (T_DIM * 64) + doff;
        const u16* vb = Vb + (size_t)s * (T_DIM * 64) + doff;
        #pragma unroll
        for (int t = 0; t < T_DIM; ++t) {
            ku[t] = *(const u32*)(kb + t * 64);
            vu[t] = *(const u32*)(vb + t * 64);
        }
        bool val = i < e1;
        const float* gp = gate + (size_t)s * T_DIM;
        float2 g01 = *(const float2*)(gp);
        float2 g23 = *(const float2*)(gp + 2);
        float2 g45 = *(const float2*)(gp + 4);
        gg[0] = val ? g01.x : NEGBIG; gg[1] = val ? g01.y : NEGBIG;
        gg[2] = val ? g23.x : NEGBIG; gg[3] = val ? g23.y : NEGBIG;
        gg[4] = val ? g45.x : NEGBIG; gg[5] = val ? g45.y : NEGBIG;
    }

    for (int p = 0; p < npairs; ++p) {
        // ---- prefetch next pair (clamped; overlaps the compute below) ----
        u32 ku2[T_DIM], vu2[T_DIM];
        float gg2[T_DIM];
        {
            int i = e0 + (p + 1) * 2 + half;
            int s = edge_src[min(i, e1 - 1)];
            const u16* kb = Kb + (size_t)s * (T_DIM * 64) + doff;
            const u16* vb = Vb + (size_t)s * (T_DIM * 64) + doff;
            #pragma unroll
            for (int t = 0; t < T_DIM; ++t) {
                ku2[t] = *(const u32*)(kb + t * 64);
                vu2[t] = *(const u32*)(vb + t * 64);
            }
            bool val = i < e1;
            const float* gp = gate + (size_t)s * T_DIM;
            float2 g01 = *(const float2*)(gp);
            float2 g23 = *(const float2*)(gp + 2);
            float2 g45 = *(const float2*)(gp + 4);
            gg2[0] = val ? g01.x : NEGBIG; gg2[1] = val ? g01.y : NEGBIG;
            gg2[2] = val ? g23.x : NEGBIG; gg2[3] = val ? g23.y : NEGBIG;
            gg2[4] = val ? g45.x : NEGBIG; gg2[5] = val ? g45.y : NEGBIG;
        }
        // ---- compute current pair ----
        float k0[T_DIM], k1[T_DIM], v0[T_DIM], v1[T_DIM];
        #pragma unroll
        for (int t = 0; t < T_DIM; ++t) {
            k0[t] = __int_as_float((int)(ku[t] << 16));
            k1[t] = __int_as_float((int)(ku[t] & 0xffff0000u));
            v0[t] = __int_as_float((int)(vu[t] << 16));
            v1[t] = __int_as_float((int)(vu[t] & 0xffff0000u));
        }
        #pragma unroll
        for (int t = 0; t < T_DIM; ++t) {
            #pragma unroll
            for (int dt = 0; dt <= t; ++dt) {
                int tp = t - dt;
                float d = red8(fmaf(q1[t], k1[tp], q0[t] * k0[tp]));
                float wt = fast_exp2(d + cc[t * (t + 1) / 2 + dt] + gg[tp]);
                den[t] += wt;
                nu0[t] = fmaf(wt, v0[tp], nu0[t]);
                nu1[t] = fmaf(wt, v1[tp], nu1[t]);
            }
        }
        #pragma unroll
        for (int t = 0; t < T_DIM; ++t) { ku[t] = ku2[t]; vu[t] = vu2[t]; gg[t] = gg2[t]; }
    }

    // combine the two edge-halves (once per node), then store
    #pragma unroll
    for (int t = 0; t < T_DIM; ++t) {
        den[t] += __shfl_xor(den[t], 32);
        nu0[t] += __shfl_xor(nu0[t], 32);
        nu1[t] += __shfl_xor(nu1[t], 32);
    }
    if (half == 0) {
        #pragma unroll
        for (int t = 0; t < T_DIM; ++t) {
            float r = 1.0f / fmaxf(den[t], 1e-12f);
            *(float2*)(out + ((size_t)t * N_NODES + n) * 64 + doff) =
                make_float2(nu0[t] * r, nu1[t] * r);
        }
    }
}

extern "C" void kernel_launch(void* const* d_in, const int* in_sizes, int n_in,
                              void* d_out, int out_size, void* d_ws, size_t ws_size,
                              hipStream_t stream) {
    const float* H  = (const float*)d_in[0];
    const float* S  = (const float*)d_in[1];
    const float* Wq = (const float*)d_in[2];
    const float* Wk = (const float*)d_in[3];
    const float* Wv = (const float*)d_in[4];
    const int* edge = (const int*)d_in[5];
    int E = in_sizes[5] / 2;
    const int* esrc = edge;
    const int* edst = edge + E;
    float* out = (float*)d_out;

    char* ws = (char*)d_ws;
    size_t off = 0;
    auto alloc = [&](size_t b) { char* p = ws + off; off += (b + 255) & ~(size_t)255; return (void*)p; };
    u16*   Kb       = (u16*)  alloc((size_t)TOTAL_ROWS * 64 * 2);   // 7.68 MB
    u16*   Vb       = (u16*)  alloc((size_t)TOTAL_ROWS * 64 * 2);   // 7.68 MB
    float* gate     = (float*)alloc((size_t)TOTAL_ROWS * 4);        // 240 KB
    float* kpe      = (float*)alloc(9 * 64 * 4);
    float* bias     = (float*)alloc(9 * 4);
    int*   row_ptr  = (int*)  alloc((size_t)(N_NODES + 1) * 4);
    int*   edge_src = (int*)  alloc((size_t)E * 4);

    int proj_blocks = (TOTAL_ROWS / 32 + 3) / 4;   // 1875 waves / 4 per block = 469
    proj_kernel<<<proj_blocks, 256, 0, stream>>>(H, S, Wq, Wk, Wv, out, Kb, Vb, gate, kpe, bias);
    csr_kernel<<<1, SCAN_THREADS, 0, stream>>>(esrc, edst, row_ptr, edge_src, E);
    agg_kernel<<<(N_NODES + 3) / 4, 256, 0, stream>>>(out, Kb, Vb, gate, kpe, bias, row_ptr, edge_src, out);
}

// Round 5
// 71.215 us; speedup vs baseline: 1.6943x; 1.6943x over previous
//
#include <hip/hip_runtime.h>
#include <hip/hip_bf16.h>

#define T_DIM 6
#define N_NODES 10000
#define TOTAL_ROWS (T_DIM * N_NODES)   // 60000
#define LOG2E 1.44269504088896340736f
#define QPRE (0.25f * LOG2E)           // dh^-0.5 * log2(e): softmax done in exp2 domain
#define EPS_GATE 1e-6f
#define NEGBIG (-1e30f)

typedef unsigned int u32;
typedef unsigned short u16;
typedef __attribute__((ext_vector_type(8))) short bf16x8;
typedef __attribute__((ext_vector_type(4))) float f32x4;

#define MFMA16(a, b, c) __builtin_amdgcn_mfma_f32_16x16x32_bf16(a, b, c, 0, 0, 0)

__device__ __forceinline__ float fast_exp2(float x) {
#if __has_builtin(__builtin_amdgcn_exp2f)
    return __builtin_amdgcn_exp2f(x);
#else
    return exp2f(x);
#endif
}

// DPP butterfly add within 8-lane groups.
template <int CTRL>
__device__ __forceinline__ float dpp_add(float x) {
    int v = __builtin_amdgcn_update_dpp(0, __float_as_int(x), CTRL, 0xf, 0xf, true);
    return x + __int_as_float(v);
}
__device__ __forceinline__ float red8(float x) {
    x = dpp_add<0xB1>(x);   // quad_perm {1,0,3,2}  : lane ^ 1
    x = dpp_add<0x4E>(x);   // quad_perm {2,3,0,1}  : lane ^ 2
    x = dpp_add<0x141>(x);  // row_half_mirror      : l -> 7-l within 8
    return x;
}

__device__ __forceinline__ float bf2f(u16 u) {
    union { unsigned int i; float f; } c;
    c.i = ((unsigned int)u) << 16;
    return c.f;
}

__device__ __forceinline__ u16 f2bf(float f) {
    union { float f; unsigned int i; } c; c.f = f;
    unsigned int i = c.i;
    unsigned int lsb = (i >> 16) & 1u;
    i += 0x7FFFu + lsb;          // round-to-nearest-even (finite data only)
    return (u16)(i >> 16);
}

// ---------------- zero counts (replaces rocclr fillBuffer: 43us -> ~2us) + kpe/bias tables ----------------
__global__ void zero_kernel(int* __restrict__ counts,
                            const float* __restrict__ Wk,
                            float* __restrict__ kpe, float* __restrict__ bias) {
    int idx = blockIdx.x * blockDim.x + threadIdx.x;
    if (idx < N_NODES) counts[idx] = 0;
    if (blockIdx.x == 0 && threadIdx.x < 64) {
        int c = threadIdx.x;
        for (int dt = 0; dt < 9; ++dt) {
            float fdt = (float)dt;
            float pe[8];
            pe[0] = expf(-fdt * 0.25f);    // tau=4
            pe[1] = expf(-fdt * 0.0625f);  // tau=16
            pe[2] = sinf(fdt * 1.0f);
            pe[3] = sinf(fdt * 0.5f);
            pe[4] = sinf(fdt * 0.25f);
            pe[5] = cosf(fdt * 1.0f);
            pe[6] = cosf(fdt * 0.5f);
            pe[7] = cosf(fdt * 0.25f);
            float acc = 0.f;
            #pragma unroll
            for (int j = 0; j < 8; ++j) acc += pe[j] * Wk[c * 72 + 64 + j];
            kpe[dt * 64 + c] = acc;
            if (c == 0) bias[dt] = -log2f(1.0f + fdt);
        }
    }
}

// ---------------- fused prep + edge-count + QKV projection via split-bf16 MFMA ----------------
// Prep: gate = log2(S+eps) transposed [n][t]; degree histogram (distributed atomics).
// GEMM: C[row, col] = sum_k H[row,k]*W[col,k], cols 0-63 Q, 64-127 K, 128-191 V.
// f32 accuracy recovered via h = hi + lo (bf16 pair): h*w ~= hi*whi + hi*wlo + lo*whi.
__global__ __launch_bounds__(256) void proj_kernel(
    const float* __restrict__ H,
    const float* __restrict__ S,
    const float* __restrict__ Wq, const float* __restrict__ Wk,
    const float* __restrict__ Wv,
    const int* __restrict__ edst, int E, int* __restrict__ counts,
    float* __restrict__ Qs, u16* __restrict__ Kb, u16* __restrict__ Vb,
    float* __restrict__ gate) {
    int tid = threadIdx.x;
    int gtid = blockIdx.x * 256 + tid;
    int gstride = gridDim.x * 256;
    // ---- fused prep ----
    if (gtid < TOTAL_ROWS) {
        int t = gtid / N_NODES, n = gtid - t * N_NODES;
        gate[n * T_DIM + t] = log2f(S[gtid] + EPS_GATE);
    }
    for (int e = gtid; e < E; e += gstride) atomicAdd(&counts[edst[e]], 1);

    // ---- weight staging ----
    __shared__ short whi[192][72];   // stride 72 shorts = 144B -> 2-way banks (free)
    __shared__ short wlo[192][72];
    for (int i = tid; i < 192 * 64; i += 256) {
        int col = i >> 6, k = i & 63;
        float w;
        if (col < 64)       w = Wq[col * 64 + k];
        else if (col < 128) w = Wk[(col - 64) * 72 + k];   // first 64 input dims of W_k
        else                w = Wv[(col - 128) * 64 + k];
        u16 hb = f2bf(w);
        u16 lb = f2bf(w - bf2f(hb));
        whi[col][k] = (short)hb;
        wlo[col][k] = (short)lb;
    }
    __syncthreads();

    int lane = tid & 63, wid = tid >> 6;
    int r0 = (blockIdx.x * 4 + wid) * 32;          // 32 rows per wave (60000 = 32*1875)
    if (r0 >= TOTAL_ROWS) return;

    int mrow = lane & 15;
    int kgrp = lane >> 4;                          // 0..3

    // A fragments: [mtile][kstep], hi+lo split
    bf16x8 ahi[2][2], alo[2][2];
    #pragma unroll
    for (int mt = 0; mt < 2; ++mt) {
        #pragma unroll
        for (int ks = 0; ks < 2; ++ks) {
            const float* hp = H + (size_t)(r0 + mt * 16 + mrow) * 64 + ks * 32 + kgrp * 8;
            float4 hA = *(const float4*)hp;
            float4 hB = *(const float4*)(hp + 4);
            float tmp[8] = {hA.x, hA.y, hA.z, hA.w, hB.x, hB.y, hB.z, hB.w};
            #pragma unroll
            for (int b = 0; b < 8; ++b) {
                u16 hb = f2bf(tmp[b]);
                u16 lb = f2bf(tmp[b] - bf2f(hb));
                ahi[mt][ks][b] = (short)hb;
                alo[mt][ks][b] = (short)lb;
            }
        }
    }

    #pragma unroll
    for (int nt = 0; nt < 12; ++nt) {
        f32x4 acc0 = {0.f, 0.f, 0.f, 0.f};
        f32x4 acc1 = {0.f, 0.f, 0.f, 0.f};
        #pragma unroll
        for (int ks = 0; ks < 2; ++ks) {
            bf16x8 bh = *(const bf16x8*)&whi[nt * 16 + mrow][ks * 32 + kgrp * 8];
            bf16x8 bl = *(const bf16x8*)&wlo[nt * 16 + mrow][ks * 32 + kgrp * 8];
            acc0 = MFMA16(ahi[0][ks], bh, acc0);
            acc0 = MFMA16(ahi[0][ks], bl, acc0);
            acc0 = MFMA16(alo[0][ks], bh, acc0);
            acc1 = MFMA16(ahi[1][ks], bh, acc1);
            acc1 = MFMA16(ahi[1][ks], bl, acc1);
            acc1 = MFMA16(alo[1][ks], bh, acc1);
        }
        // epilogue: C col = lane&15, row = (lane>>4)*4 + j   [m89-verified]
        #pragma unroll
        for (int mt = 0; mt < 2; ++mt) {
            f32x4 acc = mt ? acc1 : acc0;
            int mbase = r0 + mt * 16 + kgrp * 4;
            #pragma unroll
            for (int j = 0; j < 4; ++j) {
                int gr = mbase + j;
                float v = acc[j];
                if (nt < 4) {
                    Qs[(size_t)gr * 64 + nt * 16 + mrow] = v * QPRE;
                } else if (nt < 8) {
                    int t = gr / N_NODES, n = gr - t * N_NODES;
                    Kb[((size_t)n * T_DIM + t) * 64 + (nt - 4) * 16 + mrow] = f2bf(v);
                } else {
                    int t = gr / N_NODES, n = gr - t * N_NODES;
                    Vb[((size_t)n * T_DIM + t) * 64 + (nt - 8) * 16 + mrow] = f2bf(v);
                }
            }
        }
    }
}

// ---------------- single-block exclusive scan over 10K counts -> CSR row_ptr ----------------
#define SCAN_THREADS 1024
#define SCAN_CHUNK 10            // 1024*10 >= 10000
__global__ __launch_bounds__(SCAN_THREADS) void scan_kernel(
    const int* __restrict__ counts,
    int* __restrict__ row_ptr,   // N+1
    int* __restrict__ cursor) {
    __shared__ int sums[SCAN_THREADS];
    int tid = threadIdx.x;
    int start = tid * SCAN_CHUNK;
    int local[SCAN_CHUNK];
    int s = 0;
    #pragma unroll
    for (int j = 0; j < SCAN_CHUNK; ++j) {
        int idx = start + j;
        int v = (idx < N_NODES) ? counts[idx] : 0;
        local[j] = s; s += v;
    }
    sums[tid] = s;
    __syncthreads();
    for (int off = 1; off < SCAN_THREADS; off <<= 1) {
        int v = sums[tid];
        int o = (tid >= off) ? sums[tid - off] : 0;
        __syncthreads();
        sums[tid] = v + o;
        __syncthreads();
    }
    int base = (tid > 0) ? sums[tid - 1] : 0;
    #pragma unroll
    for (int j = 0; j < SCAN_CHUNK; ++j) {
        int idx = start + j;
        if (idx < N_NODES) {
            int val = base + local[j];
            row_ptr[idx] = val;
            cursor[idx] = val;
        }
    }
    if (tid == SCAN_THREADS - 1) row_ptr[N_NODES] = sums[SCAN_THREADS - 1];
}

// ---------------- scatter edges into CSR buckets (distributed atomics) ----------------
__global__ void scatter_kernel(const int* __restrict__ esrc, const int* __restrict__ edst,
                               int* __restrict__ cursor, int* __restrict__ edge_src, int E) {
    int e = blockIdx.x * blockDim.x + threadIdx.x;
    if (e < E) {
        int pos = atomicAdd(&cursor[edst[e]], 1);
        edge_src[pos] = esrc[e];
    }
}

// ---------------- aggregation: one wave per node, 2 edges per iteration ----------------
// lanes: [half(2 edges)][head(4)][pair(8)], each lane owns 2 consecutive dims.
__global__ __launch_bounds__(256) void agg_kernel(
    const float* __restrict__ Qs,     // [t][n][64], prescaled by QPRE (aliases out)
    const u16* __restrict__ Kb,       // [n][t][64] bf16
    const u16* __restrict__ Vb,
    const float* __restrict__ gate,   // [n][t]  log2(S+eps)
    const float* __restrict__ kpe,    // [9][64]
    const float* __restrict__ bias,   // [9]  -log2(1+dt)
    const int* __restrict__ row_ptr,
    const int* __restrict__ edge_src,
    float* __restrict__ out) {
    int lane = threadIdx.x & 63, w = threadIdx.x >> 6;
    int n = blockIdx.x * 4 + w;
    int half = lane >> 5;
    int l32 = lane & 31;
    int doff = ((l32 >> 3) << 4) + ((l32 & 7) << 1);   // h*16 + 2*p

    float q0[T_DIM], q1[T_DIM];
    #pragma unroll
    for (int t = 0; t < T_DIM; ++t) {
        float2 qq = *(const float2*)(Qs + ((size_t)t * N_NODES + n) * 64 + doff);
        q0[t] = qq.x; q1[t] = qq.y;
    }

    int e0 = row_ptr[n], e1 = row_ptr[n + 1];
    if (e0 >= e1) {                                    // zero-degree: output 0 (matches ref clip)
        if (half == 0) {
            #pragma unroll
            for (int t = 0; t < T_DIM; ++t)
                *(float2*)(out + ((size_t)t * N_NODES + n) * 64 + doff) = make_float2(0.f, 0.f);
        }
        return;
    }

    // cc[tri(t,dt)] = dot(q[t], K_pe[dt]) + bias[dt]   (log2 domain; uniform per head group)
    float cc[21];
    #pragma unroll
    for (int dt = 0; dt < T_DIM; ++dt) {
        float2 kp = *(const float2*)(kpe + dt * 64 + doff);
        float b = bias[dt];
        #pragma unroll
        for (int t = dt; t < T_DIM; ++t)
            cc[t * (t + 1) / 2 + dt] = red8(fmaf(q1[t], kp.y, q0[t] * kp.x)) + b;
    }

    float den[T_DIM] = {0,0,0,0,0,0};
    float nu0[T_DIM] = {0,0,0,0,0,0};
    float nu1[T_DIM] = {0,0,0,0,0,0};

    int npairs = (e1 - e0 + 1) >> 1;
    u32 ku[T_DIM], vu[T_DIM];
    float gg[T_DIM];

    // prologue: load pair 0 (this half's edge; odd tail padded via g = -1e30 -> weight 0)
    {
        int i = e0 + half;
        int s = edge_src[min(i, e1 - 1)];
        const u16* kb = Kb + (size_t)s * (T_DIM * 64) + doff;
        const u16* vb = Vb + (size_t)s * (T_DIM * 64) + doff;
        #pragma unroll
        for (int t = 0; t < T_DIM; ++t) {
            ku[t] = *(const u32*)(kb + t * 64);
            vu[t] = *(const u32*)(vb + t * 64);
        }
        bool val = i < e1;
        const float* gp = gate + (size_t)s * T_DIM;
        float2 g01 = *(const float2*)(gp);
        float2 g23 = *(const float2*)(gp + 2);
        float2 g45 = *(const float2*)(gp + 4);
        gg[0] = val ? g01.x : NEGBIG; gg[1] = val ? g01.y : NEGBIG;
        gg[2] = val ? g23.x : NEGBIG; gg[3] = val ? g23.y : NEGBIG;
        gg[4] = val ? g45.x : NEGBIG; gg[5] = val ? g45.y : NEGBIG;
    }

    for (int p = 0; p < npairs; ++p) {
        // ---- prefetch next pair (clamped; overlaps the compute below) ----
        u32 ku2[T_DIM], vu2[T_DIM];
        float gg2[T_DIM];
        {
            int i = e0 + (p + 1) * 2 + half;
            int s = edge_src[min(i, e1 - 1)];
            const u16* kb = Kb + (size_t)s * (T_DIM * 64) + doff;
            const u16* vb = Vb + (size_t)s * (T_DIM * 64) + doff;
            #pragma unroll
            for (int t = 0; t < T_DIM; ++t) {
                ku2[t] = *(const u32*)(kb + t * 64);
                vu2[t] = *(const u32*)(vb + t * 64);
            }
            bool val = i < e1;
            const float* gp = gate + (size_t)s * T_DIM;
            float2 g01 = *(const float2*)(gp);
            float2 g23 = *(const float2*)(gp + 2);
            float2 g45 = *(const float2*)(gp + 4);
            gg2[0] = val ? g01.x : NEGBIG; gg2[1] = val ? g01.y : NEGBIG;
            gg2[2] = val ? g23.x : NEGBIG; gg2[3] = val ? g23.y : NEGBIG;
            gg2[4] = val ? g45.x : NEGBIG; gg2[5] = val ? g45.y : NEGBIG;
        }
        // ---- compute current pair ----
        float k0[T_DIM], k1[T_DIM], v0[T_DIM], v1[T_DIM];
        #pragma unroll
        for (int t = 0; t < T_DIM; ++t) {
            k0[t] = __int_as_float((int)(ku[t] << 16));
            k1[t] = __int_as_float((int)(ku[t] & 0xffff0000u));
            v0[t] = __int_as_float((int)(vu[t] << 16));
            v1[t] = __int_as_float((int)(vu[t] & 0xffff0000u));
        }
        #pragma unroll
        for (int t = 0; t < T_DIM; ++t) {
            #pragma unroll
            for (int dt = 0; dt <= t; ++dt) {
                int tp = t - dt;
                float d = red8(fmaf(q1[t], k1[tp], q0[t] * k0[tp]));
                float wt = fast_exp2(d + cc[t * (t + 1) / 2 + dt] + gg[tp]);
                den[t] += wt;
                nu0[t] = fmaf(wt, v0[tp], nu0[t]);
                nu1[t] = fmaf(wt, v1[tp], nu1[t]);
            }
        }
        #pragma unroll
        for (int t = 0; t < T_DIM; ++t) { ku[t] = ku2[t]; vu[t] = vu2[t]; gg[t] = gg2[t]; }
    }

    // combine the two edge-halves (once per node), then store
    #pragma unroll
    for (int t = 0; t < T_DIM; ++t) {
        den[t] += __shfl_xor(den[t], 32);
        nu0[t] += __shfl_xor(nu0[t], 32);
        nu1[t] += __shfl_xor(nu1[t], 32);
    }
    if (half == 0) {
        #pragma unroll
        for (int t = 0; t < T_DIM; ++t) {
            float r = 1.0f / fmaxf(den[t], 1e-12f);
            *(float2*)(out + ((size_t)t * N_NODES + n) * 64 + doff) =
                make_float2(nu0[t] * r, nu1[t] * r);
        }
    }
}

extern "C" void kernel_launch(void* const* d_in, const int* in_sizes, int n_in,
                              void* d_out, int out_size, void* d_ws, size_t ws_size,
                              hipStream_t stream) {
    const float* H  = (const float*)d_in[0];
    const float* S  = (const float*)d_in[1];
    const float* Wq = (const float*)d_in[2];
    const float* Wk = (const float*)d_in[3];
    const float* Wv = (const float*)d_in[4];
    const int* edge = (const int*)d_in[5];
    int E = in_sizes[5] / 2;
    const int* esrc = edge;
    const int* edst = edge + E;
    float* out = (float*)d_out;

    char* ws = (char*)d_ws;
    size_t off = 0;
    auto alloc = [&](size_t b) { char* p = ws + off; off += (b + 255) & ~(size_t)255; return (void*)p; };
    u16*   Kb       = (u16*)  alloc((size_t)TOTAL_ROWS * 64 * 2);   // 7.68 MB
    u16*   Vb       = (u16*)  alloc((size_t)TOTAL_ROWS * 64 * 2);   // 7.68 MB
    float* gate     = (float*)alloc((size_t)TOTAL_ROWS * 4);        // 240 KB
    float* kpe      = (float*)alloc(9 * 64 * 4);
    float* bias     = (float*)alloc(9 * 4);
    int*   counts   = (int*)  alloc((size_t)N_NODES * 4);
    int*   cursor   = (int*)  alloc((size_t)N_NODES * 4);
    int*   row_ptr  = (int*)  alloc((size_t)(N_NODES + 1) * 4);
    int*   edge_src = (int*)  alloc((size_t)E * 4);

    zero_kernel<<<(N_NODES + 255) / 256, 256, 0, stream>>>(counts, Wk, kpe, bias);
    int proj_blocks = (TOTAL_ROWS / 32 + 3) / 4;   // 469
    proj_kernel<<<proj_blocks, 256, 0, stream>>>(H, S, Wq, Wk, Wv, edst, E, counts, out, Kb, Vb, gate);
    scan_kernel<<<1, SCAN_THREADS, 0, stream>>>(counts, row_ptr, cursor);
    scatter_kernel<<<(E + 255) / 256, 256, 0, stream>>>(esrc, edst, cursor, edge_src, E);
    agg_kernel<<<(N_NODES + 3) / 4, 256, 0, stream>>>(out, Kb, Vb, gate, kpe, bias, row_ptr, edge_src, out);
}

// Round 6
// 70.144 us; speedup vs baseline: 1.7202x; 1.0153x over previous
//
#include <hip/hip_runtime.h>
#include <hip/hip_bf16.h>

#define T_DIM 6
#define N_NODES 10000
#define TOTAL_ROWS (T_DIM * N_NODES)   // 60000
#define LOG2E 1.44269504088896340736f
#define QPRE (0.25f * LOG2E)           // dh^-0.5 * log2(e): softmax done in exp2 domain
#define EPS_GATE 1e-6f
#define NEGBIG (-1e30f)

typedef unsigned int u32;
typedef unsigned short u16;
typedef __attribute__((ext_vector_type(8))) short bf16x8;
typedef __attribute__((ext_vector_type(4))) float f32x4;

#define MFMA16(a, b, c) __builtin_amdgcn_mfma_f32_16x16x32_bf16(a, b, c, 0, 0, 0)

__device__ __forceinline__ float fast_exp2(float x) {
#if __has_builtin(__builtin_amdgcn_exp2f)
    return __builtin_amdgcn_exp2f(x);
#else
    return exp2f(x);
#endif
}

// DPP butterfly add within 4-lane quads.
template <int CTRL>
__device__ __forceinline__ float dpp_add(float x) {
    int v = __builtin_amdgcn_update_dpp(0, __float_as_int(x), CTRL, 0xf, 0xf, true);
    return x + __int_as_float(v);
}
__device__ __forceinline__ float red4(float x) {
    x = dpp_add<0xB1>(x);   // quad_perm {1,0,3,2} : lane ^ 1
    x = dpp_add<0x4E>(x);   // quad_perm {2,3,0,1} : lane ^ 2
    return x;               // all 4 lanes of the quad hold the sum
}

__device__ __forceinline__ float bf2f(u16 u) {
    union { unsigned int i; float f; } c;
    c.i = ((unsigned int)u) << 16;
    return c.f;
}

__device__ __forceinline__ u16 f2bf(float f) {
    union { float f; unsigned int i; } c; c.f = f;
    unsigned int i = c.i;
    unsigned int lsb = (i >> 16) & 1u;
    i += 0x7FFFu + lsb;          // round-to-nearest-even (finite data only)
    return (u16)(i >> 16);
}

// ---------------- zero counts (replaces rocclr fillBuffer) + kpe/bias tables ----------------
__global__ void zero_kernel(int* __restrict__ counts,
                            const float* __restrict__ Wk,
                            float* __restrict__ kpe, float* __restrict__ bias) {
    int idx = blockIdx.x * blockDim.x + threadIdx.x;
    if (idx < N_NODES) counts[idx] = 0;
    if (blockIdx.x == 0 && threadIdx.x < 64) {
        int c = threadIdx.x;
        for (int dt = 0; dt < 9; ++dt) {
            float fdt = (float)dt;
            float pe[8];
            pe[0] = expf(-fdt * 0.25f);    // tau=4
            pe[1] = expf(-fdt * 0.0625f);  // tau=16
            pe[2] = sinf(fdt * 1.0f);
            pe[3] = sinf(fdt * 0.5f);
            pe[4] = sinf(fdt * 0.25f);
            pe[5] = cosf(fdt * 1.0f);
            pe[6] = cosf(fdt * 0.5f);
            pe[7] = cosf(fdt * 0.25f);
            float acc = 0.f;
            #pragma unroll
            for (int j = 0; j < 8; ++j) acc += pe[j] * Wk[c * 72 + 64 + j];
            kpe[dt * 64 + c] = acc;
            if (c == 0) bias[dt] = -log2f(1.0f + fdt);
        }
    }
}

// ---------------- fused prep + edge-count + QKV projection via split-bf16 MFMA ----------------
__global__ __launch_bounds__(256) void proj_kernel(
    const float* __restrict__ H,
    const float* __restrict__ S,
    const float* __restrict__ Wq, const float* __restrict__ Wk,
    const float* __restrict__ Wv,
    const int* __restrict__ edst, int E, int* __restrict__ counts,
    float* __restrict__ Qs, u16* __restrict__ Kb, u16* __restrict__ Vb,
    float* __restrict__ gate) {
    int tid = threadIdx.x;
    int gtid = blockIdx.x * 256 + tid;
    int gstride = gridDim.x * 256;
    // ---- fused prep ----
    if (gtid < TOTAL_ROWS) {
        int t = gtid / N_NODES, n = gtid - t * N_NODES;
        gate[n * T_DIM + t] = log2f(S[gtid] + EPS_GATE);
    }
    for (int e = gtid; e < E; e += gstride) atomicAdd(&counts[edst[e]], 1);

    // ---- weight staging ----
    __shared__ short whi[192][72];   // stride 72 shorts = 144B -> 2-way banks (free)
    __shared__ short wlo[192][72];
    for (int i = tid; i < 192 * 64; i += 256) {
        int col = i >> 6, k = i & 63;
        float w;
        if (col < 64)       w = Wq[col * 64 + k];
        else if (col < 128) w = Wk[(col - 64) * 72 + k];   // first 64 input dims of W_k
        else                w = Wv[(col - 128) * 64 + k];
        u16 hb = f2bf(w);
        u16 lb = f2bf(w - bf2f(hb));
        whi[col][k] = (short)hb;
        wlo[col][k] = (short)lb;
    }
    __syncthreads();

    int lane = tid & 63, wid = tid >> 6;
    int r0 = (blockIdx.x * 4 + wid) * 32;          // 32 rows per wave (60000 = 32*1875)
    if (r0 >= TOTAL_ROWS) return;

    int mrow = lane & 15;
    int kgrp = lane >> 4;                          // 0..3

    // A fragments: [mtile][kstep], hi+lo split
    bf16x8 ahi[2][2], alo[2][2];
    #pragma unroll
    for (int mt = 0; mt < 2; ++mt) {
        #pragma unroll
        for (int ks = 0; ks < 2; ++ks) {
            const float* hp = H + (size_t)(r0 + mt * 16 + mrow) * 64 + ks * 32 + kgrp * 8;
            float4 hA = *(const float4*)hp;
            float4 hB = *(const float4*)(hp + 4);
            float tmp[8] = {hA.x, hA.y, hA.z, hA.w, hB.x, hB.y, hB.z, hB.w};
            #pragma unroll
            for (int b = 0; b < 8; ++b) {
                u16 hb = f2bf(tmp[b]);
                u16 lb = f2bf(tmp[b] - bf2f(hb));
                ahi[mt][ks][b] = (short)hb;
                alo[mt][ks][b] = (short)lb;
            }
        }
    }

    #pragma unroll
    for (int nt = 0; nt < 12; ++nt) {
        f32x4 acc0 = {0.f, 0.f, 0.f, 0.f};
        f32x4 acc1 = {0.f, 0.f, 0.f, 0.f};
        #pragma unroll
        for (int ks = 0; ks < 2; ++ks) {
            bf16x8 bh = *(const bf16x8*)&whi[nt * 16 + mrow][ks * 32 + kgrp * 8];
            bf16x8 bl = *(const bf16x8*)&wlo[nt * 16 + mrow][ks * 32 + kgrp * 8];
            acc0 = MFMA16(ahi[0][ks], bh, acc0);
            acc0 = MFMA16(ahi[0][ks], bl, acc0);
            acc0 = MFMA16(alo[0][ks], bh, acc0);
            acc1 = MFMA16(ahi[1][ks], bh, acc1);
            acc1 = MFMA16(ahi[1][ks], bl, acc1);
            acc1 = MFMA16(alo[1][ks], bh, acc1);
        }
        // epilogue: C col = lane&15, row = (lane>>4)*4 + j   [m89-verified]
        #pragma unroll
        for (int mt = 0; mt < 2; ++mt) {
            f32x4 acc = mt ? acc1 : acc0;
            int mbase = r0 + mt * 16 + kgrp * 4;
            #pragma unroll
            for (int j = 0; j < 4; ++j) {
                int gr = mbase + j;
                float v = acc[j];
                if (nt < 4) {
                    Qs[(size_t)gr * 64 + nt * 16 + mrow] = v * QPRE;
                } else if (nt < 8) {
                    int t = gr / N_NODES, n = gr - t * N_NODES;
                    Kb[((size_t)n * T_DIM + t) * 64 + (nt - 4) * 16 + mrow] = f2bf(v);
                } else {
                    int t = gr / N_NODES, n = gr - t * N_NODES;
                    Vb[((size_t)n * T_DIM + t) * 64 + (nt - 8) * 16 + mrow] = f2bf(v);
                }
            }
        }
    }
}

// ---------------- single-block exclusive scan over 10K counts -> CSR row_ptr ----------------
#define SCAN_THREADS 1024
#define SCAN_CHUNK 10            // 1024*10 >= 10000
__global__ __launch_bounds__(SCAN_THREADS) void scan_kernel(
    const int* __restrict__ counts,
    int* __restrict__ row_ptr,   // N+1
    int* __restrict__ cursor) {
    __shared__ int sums[SCAN_THREADS];
    int tid = threadIdx.x;
    int start = tid * SCAN_CHUNK;
    int local[SCAN_CHUNK];
    int s = 0;
    #pragma unroll
    for (int j = 0; j < SCAN_CHUNK; ++j) {
        int idx = start + j;
        int v = (idx < N_NODES) ? counts[idx] : 0;
        local[j] = s; s += v;
    }
    sums[tid] = s;
    __syncthreads();
    for (int off = 1; off < SCAN_THREADS; off <<= 1) {
        int v = sums[tid];
        int o = (tid >= off) ? sums[tid - off] : 0;
        __syncthreads();
        sums[tid] = v + o;
        __syncthreads();
    }
    int base = (tid > 0) ? sums[tid - 1] : 0;
    #pragma unroll
    for (int j = 0; j < SCAN_CHUNK; ++j) {
        int idx = start + j;
        if (idx < N_NODES) {
            int val = base + local[j];
            row_ptr[idx] = val;
            cursor[idx] = val;
        }
    }
    if (tid == SCAN_THREADS - 1) row_ptr[N_NODES] = sums[SCAN_THREADS - 1];
}

// ---------------- scatter edges into CSR buckets (distributed atomics) ----------------
__global__ void scatter_kernel(const int* __restrict__ esrc, const int* __restrict__ edst,
                               int* __restrict__ cursor, int* __restrict__ edge_src, int E) {
    int e = blockIdx.x * blockDim.x + threadIdx.x;
    if (e < E) {
        int pos = atomicAdd(&cursor[edst[e]], 1);
        edge_src[pos] = esrc[e];
    }
}

// ---------------- aggregation: one wave per node, 4 edges per iteration ----------------
// lane = e4*16 + h*4 + dg : edge-group(4) x head(4) x dim-group(4); lane owns 4 dims.
// dot-16 reduce = red4 (2 quad_perm DPP adds, within the 4-lane quad).
__global__ __launch_bounds__(256) void agg_kernel(
    const float* __restrict__ Qs,     // [t][n][64], prescaled by QPRE (aliases out)
    const u16* __restrict__ Kb,       // [n][t][64] bf16
    const u16* __restrict__ Vb,
    const float* __restrict__ gate,   // [n][t]  log2(S+eps)
    const float* __restrict__ kpe,    // [9][64]
    const float* __restrict__ bias,   // [9]  -log2(1+dt)
    const int* __restrict__ row_ptr,
    const int* __restrict__ edge_src,
    float* __restrict__ out) {
    int lane = threadIdx.x & 63, w = threadIdx.x >> 6;
    int n = blockIdx.x * 4 + w;
    int e4 = lane >> 4;                      // which of 4 edges
    int doff = (lane & 15) << 2;             // h*16 + dg*4 = 4*(lane&15)

    float4 q[T_DIM];
    #pragma unroll
    for (int t = 0; t < T_DIM; ++t)
        q[t] = *(const float4*)(Qs + ((size_t)t * N_NODES + n) * 64 + doff);

    int e0 = row_ptr[n], e1 = row_ptr[n + 1];
    if (e0 >= e1) {                          // zero-degree: output 0 (matches ref clip)
        if (e4 == 0) {
            #pragma unroll
            for (int t = 0; t < T_DIM; ++t)
                *(float4*)(out + ((size_t)t * N_NODES + n) * 64 + doff) =
                    make_float4(0.f, 0.f, 0.f, 0.f);
        }
        return;
    }

    // cc[tri(t,dt)] = dot16(q[t], K_pe[dt]) + bias[dt]  (uniform within each quad)
    float cc[21];
    #pragma unroll
    for (int dt = 0; dt < T_DIM; ++dt) {
        float4 kp = *(const float4*)(kpe + dt * 64 + doff);
        float b = bias[dt];
        #pragma unroll
        for (int t = dt; t < T_DIM; ++t) {
            float part = q[t].x * kp.x;
            part = fmaf(q[t].y, kp.y, part);
            part = fmaf(q[t].z, kp.z, part);
            part = fmaf(q[t].w, kp.w, part);
            cc[t * (t + 1) / 2 + dt] = red4(part) + b;
        }
    }

    float den[T_DIM] = {0,0,0,0,0,0};
    float4 nu[T_DIM];
    #pragma unroll
    for (int t = 0; t < T_DIM; ++t) nu[t] = make_float4(0.f, 0.f, 0.f, 0.f);

    int nq = (e1 - e0 + 3) >> 2;
    uint2 ku[T_DIM], vu[T_DIM];
    float gg[T_DIM];

    // prologue: load quad 0 (this group's edge; invalid edges -> g = -1e30 -> weight 0)
    {
        int idx = e0 + e4;
        int s = edge_src[min(idx, e1 - 1)];
        const u16* kb = Kb + (size_t)s * (T_DIM * 64) + doff;
        const u16* vb = Vb + (size_t)s * (T_DIM * 64) + doff;
        #pragma unroll
        for (int t = 0; t < T_DIM; ++t) {
            ku[t] = *(const uint2*)(kb + t * 64);
            vu[t] = *(const uint2*)(vb + t * 64);
        }
        bool val = idx < e1;
        const float* gp = gate + (size_t)s * T_DIM;
        float2 g01 = *(const float2*)(gp);
        float2 g23 = *(const float2*)(gp + 2);
        float2 g45 = *(const float2*)(gp + 4);
        gg[0] = val ? g01.x : NEGBIG; gg[1] = val ? g01.y : NEGBIG;
        gg[2] = val ? g23.x : NEGBIG; gg[3] = val ? g23.y : NEGBIG;
        gg[4] = val ? g45.x : NEGBIG; gg[5] = val ? g45.y : NEGBIG;
    }

    for (int p = 0; p < nq; ++p) {
        // ---- prefetch next quad (clamped; overlaps the compute below) ----
        uint2 ku2[T_DIM], vu2[T_DIM];
        float gg2[T_DIM];
        {
            int idx = e0 + (p + 1) * 4 + e4;
            int s = edge_src[min(idx, e1 - 1)];
            const u16* kb = Kb + (size_t)s * (T_DIM * 64) + doff;
            const u16* vb = Vb + (size_t)s * (T_DIM * 64) + doff;
            #pragma unroll
            for (int t = 0; t < T_DIM; ++t) {
                ku2[t] = *(const uint2*)(kb + t * 64);
                vu2[t] = *(const uint2*)(vb + t * 64);
            }
            bool val = idx < e1;
            const float* gp = gate + (size_t)s * T_DIM;
            float2 g01 = *(const float2*)(gp);
            float2 g23 = *(const float2*)(gp + 2);
            float2 g45 = *(const float2*)(gp + 4);
            gg2[0] = val ? g01.x : NEGBIG; gg2[1] = val ? g01.y : NEGBIG;
            gg2[2] = val ? g23.x : NEGBIG; gg2[3] = val ? g23.y : NEGBIG;
            gg2[4] = val ? g45.x : NEGBIG; gg2[5] = val ? g45.y : NEGBIG;
        }
        // ---- compute current quad: tp-outer keeps only one K/V row unpacked ----
        #pragma unroll
        for (int tp = 0; tp < T_DIM; ++tp) {
            float k0 = __int_as_float((int)(ku[tp].x << 16));
            float k1 = __int_as_float((int)(ku[tp].x & 0xffff0000u));
            float k2 = __int_as_float((int)(ku[tp].y << 16));
            float k3 = __int_as_float((int)(ku[tp].y & 0xffff0000u));
            float v0 = __int_as_float((int)(vu[tp].x << 16));
            float v1 = __int_as_float((int)(vu[tp].x & 0xffff0000u));
            float v2 = __int_as_float((int)(vu[tp].y << 16));
            float v3 = __int_as_float((int)(vu[tp].y & 0xffff0000u));
            float g = gg[tp];
            #pragma unroll
            for (int t = tp; t < T_DIM; ++t) {
                int dt = t - tp;
                float part = q[t].x * k0;
                part = fmaf(q[t].y, k1, part);
                part = fmaf(q[t].z, k2, part);
                part = fmaf(q[t].w, k3, part);
                float d = red4(part);
                float wt = fast_exp2(d + cc[t * (t + 1) / 2 + dt] + g);
                den[t] += wt;
                nu[t].x = fmaf(wt, v0, nu[t].x);
                nu[t].y = fmaf(wt, v1, nu[t].y);
                nu[t].z = fmaf(wt, v2, nu[t].z);
                nu[t].w = fmaf(wt, v3, nu[t].w);
            }
        }
        #pragma unroll
        for (int t = 0; t < T_DIM; ++t) { ku[t] = ku2[t]; vu[t] = vu2[t]; gg[t] = gg2[t]; }
    }

    // combine the four edge-groups (once per node), then store
    #pragma unroll
    for (int t = 0; t < T_DIM; ++t) {
        den[t] += __shfl_xor(den[t], 16);  den[t] += __shfl_xor(den[t], 32);
        nu[t].x += __shfl_xor(nu[t].x, 16); nu[t].x += __shfl_xor(nu[t].x, 32);
        nu[t].y += __shfl_xor(nu[t].y, 16); nu[t].y += __shfl_xor(nu[t].y, 32);
        nu[t].z += __shfl_xor(nu[t].z, 16); nu[t].z += __shfl_xor(nu[t].z, 32);
        nu[t].w += __shfl_xor(nu[t].w, 16); nu[t].w += __shfl_xor(nu[t].w, 32);
    }
    if (e4 == 0) {
        #pragma unroll
        for (int t = 0; t < T_DIM; ++t) {
            float r = 1.0f / fmaxf(den[t], 1e-12f);
            *(float4*)(out + ((size_t)t * N_NODES + n) * 64 + doff) =
                make_float4(nu[t].x * r, nu[t].y * r, nu[t].z * r, nu[t].w * r);
        }
    }
}

extern "C" void kernel_launch(void* const* d_in, const int* in_sizes, int n_in,
                              void* d_out, int out_size, void* d_ws, size_t ws_size,
                              hipStream_t stream) {
    const float* H  = (const float*)d_in[0];
    const float* S  = (const float*)d_in[1];
    const float* Wq = (const float*)d_in[2];
    const float* Wk = (const float*)d_in[3];
    const float* Wv = (const float*)d_in[4];
    const int* edge = (const int*)d_in[5];
    int E = in_sizes[5] / 2;
    const int* esrc = edge;
    const int* edst = edge + E;
    float* out = (float*)d_out;

    char* ws = (char*)d_ws;
    size_t off = 0;
    auto alloc = [&](size_t b) { char* p = ws + off; off += (b + 255) & ~(size_t)255; return (void*)p; };
    u16*   Kb       = (u16*)  alloc((size_t)TOTAL_ROWS * 64 * 2);   // 7.68 MB
    u16*   Vb       = (u16*)  alloc((size_t)TOTAL_ROWS * 64 * 2);   // 7.68 MB
    float* gate     = (float*)alloc((size_t)TOTAL_ROWS * 4);        // 240 KB
    float* kpe      = (float*)alloc(9 * 64 * 4);
    float* bias     = (float*)alloc(9 * 4);
    int*   counts   = (int*)  alloc((size_t)N_NODES * 4);
    int*   cursor   = (int*)  alloc((size_t)N_NODES * 4);
    int*   row_ptr  = (int*)  alloc((size_t)(N_NODES + 1) * 4);
    int*   edge_src = (int*)  alloc((size_t)E * 4);

    zero_kernel<<<(N_NODES + 255) / 256, 256, 0, stream>>>(counts, Wk, kpe, bias);
    int proj_blocks = (TOTAL_ROWS / 32 + 3) / 4;   // 469
    proj_kernel<<<proj_blocks, 256, 0, stream>>>(H, S, Wq, Wk, Wv, edst, E, counts, out, Kb, Vb, gate);
    scan_kernel<<<1, SCAN_THREADS, 0, stream>>>(counts, row_ptr, cursor);
    scatter_kernel<<<(E + 255) / 256, 256, 0, stream>>>(esrc, edst, cursor, edge_src, E);
    agg_kernel<<<(N_NODES + 3) / 4, 256, 0, stream>>>(out, Kb, Vb, gate, kpe, bias, row_ptr, edge_src, out);
}